// Round 15
// baseline (190.319 us; speedup 1.0000x reference)
//
#include <hip/hip_runtime.h>

typedef __attribute__((ext_vector_type(8))) __bf16 bf16x8;
typedef __attribute__((ext_vector_type(8))) unsigned short u16x8;
typedef __attribute__((ext_vector_type(4))) float f32x4;
typedef __attribute__((ext_vector_type(4))) unsigned int u32x4;

#define LOG2E 1.4426950408889634f

// async global -> LDS, 16 bytes per lane (dest must be wave-uniform base + lane*16)
#define GLDS16(gp, lp)                                                \
  __builtin_amdgcn_global_load_lds(                                   \
      (const __attribute__((address_space(1))) void*)(gp),            \
      (__attribute__((address_space(3))) void*)(lp), 16, 0, 0)

__device__ __forceinline__ unsigned short f2b(float f) {
  return __builtin_bit_cast(unsigned short, (__bf16)f);
}
__device__ __forceinline__ float b2f(unsigned short h) {
  return __uint_as_float(((unsigned)h) << 16);
}
// v_cvt_pk_bf16_f32: lo16 = bf16(a), hi16 = bf16(b)   (no builtin on gfx950)
__device__ __forceinline__ unsigned cvt_pk(float a, float b) {
  unsigned r;
  asm("v_cvt_pk_bf16_f32 %0, %1, %2" : "=v"(r) : "v"(a), "v"(b));
  return r;
}
__device__ __forceinline__ void swap32(unsigned& a, unsigned& b) {
  asm("v_permlane32_swap_b32 %0, %1" : "+v"(a), "+v"(b));
}
__device__ __forceinline__ void swap16(unsigned& a, unsigned& b) {
  asm("v_permlane16_swap_b32 %0, %1" : "+v"(a), "+v"(b));
}
// raw v_exp_f32 (args bounded; -1e30 -> 0 is the exact HW behavior)
__device__ __forceinline__ float exp2_fast(float x) {
#if __has_builtin(__builtin_amdgcn_exp2f)
  return __builtin_amdgcn_exp2f(x);
#else
  float r; asm("v_exp_f32 %0, %1" : "=v"(r) : "v"(x)); return r;
#endif
}

// -- 1) merged launch: [0,1024) xv: xb=bf16(x), v=x@v_tmp; [1024,1536) W transpose
__global__ __launch_bounds__(256) void k_pre(const float* __restrict__ x,
                                             const float* __restrict__ vt,
                                             const float* __restrict__ W,
                                             unsigned short* __restrict__ xb,
                                             unsigned short* __restrict__ vb,
                                             unsigned short* __restrict__ Wt) {
  if (blockIdx.x < 1024) {
    __shared__ float s_vt[256];
    s_vt[threadIdx.x] = vt[threadIdx.x];
    __syncthreads();
    int g = blockIdx.x * 256 + threadIdx.x;
    int bt = g >> 6, d = g & 63;
    const float* xp = x + (size_t)bt * 1024 + d;
    float xi[16];
#pragma unroll
    for (int i = 0; i < 16; ++i) xi[i] = xp[i * 64];
#pragma unroll
    for (int i = 0; i < 16; ++i) xb[(size_t)bt * 1024 + i * 64 + d] = f2b(xi[i]);
#pragma unroll
    for (int j = 0; j < 16; ++j) {
      float s = 0.f;
#pragma unroll
      for (int i = 0; i < 16; ++i) s += xi[i] * s_vt[i * 16 + j];
      vb[(size_t)bt * 1024 + j * 64 + d] = f2b(s);
    }
  } else {
    __shared__ unsigned short tile[64][65];
    int id2 = blockIdx.x - 1024;
    int n0 = (id2 & 31) * 64;
    int k0 = (id2 >> 5) * 64;
    int tx = threadIdx.x & 63, ty = threadIdx.x >> 6;
#pragma unroll
    for (int r = 0; r < 16; ++r) {
      int kk = ty * 16 + r;
      tile[kk][tx] = f2b(W[(size_t)(k0 + kk) * 2048 + n0 + tx]);
    }
    __syncthreads();
#pragma unroll
    for (int r = 0; r < 16; ++r) {
      int nn = ty * 16 + r;
      Wt[(size_t)(n0 + nn) * 1024 + k0 + tx] = tile[tx][nn];
    }
  }
}

// -- 2) merged launch: [0,512) GEMM qk = xb @ Wt^T (m97 DMA, 128x128);
//      [512,1536) vb -> Vt transpose (t-major for PV)
__global__ __launch_bounds__(256) void k_mid(const unsigned short* __restrict__ A,
                                             const unsigned short* __restrict__ Bt,
                                             unsigned short* __restrict__ C,
                                             const unsigned short* __restrict__ vb,
                                             unsigned short* __restrict__ Vt) {
  if (blockIdx.x < 512) {
    __shared__ unsigned short As[128 * 32];
    __shared__ unsigned short Bs[128 * 32];
    const int K = 1024;
    int m0 = (blockIdx.x & 31) * 128;
    int n0 = (blockIdx.x >> 5) * 128;
    int tid = threadIdx.x;
    int w = tid >> 6, lane = tid & 63;
    int lq = lane & 15, lk8 = (lane >> 4) * 8;
    int wr = (w >> 1) * 64, wc = (w & 1) * 64;
    f32x4 acc[4][4];
#pragma unroll
    for (int i = 0; i < 4; ++i)
#pragma unroll
      for (int j = 0; j < 4; ++j)
#pragma unroll
        for (int r = 0; r < 4; ++r) acc[i][j][r] = 0.f;

    for (int kk = 0; kk < K; kk += 32) {
      __syncthreads();
#pragma unroll
      for (int i = 0; i < 2; ++i) {
        int c = tid + 256 * i;
        int row = c >> 2, col = (c & 3) * 8;
        GLDS16(A + (size_t)(m0 + row) * K + kk + col, As + c * 8);
        GLDS16(Bt + (size_t)(n0 + row) * K + kk + col, Bs + c * 8);
      }
      __syncthreads();
      bf16x8 af[4], bf[4];
#pragma unroll
      for (int i = 0; i < 4; ++i) af[i] = *(const bf16x8*)(As + (wr + i * 16 + lq) * 32 + lk8);
#pragma unroll
      for (int j = 0; j < 4; ++j) bf[j] = *(const bf16x8*)(Bs + (wc + j * 16 + lq) * 32 + lk8);
#pragma unroll
      for (int i = 0; i < 4; ++i)
#pragma unroll
        for (int j = 0; j < 4; ++j)
          acc[i][j] = __builtin_amdgcn_mfma_f32_16x16x32_bf16(af[i], bf[j], acc[i][j], 0, 0, 0);
    }
#pragma unroll
    for (int i = 0; i < 4; ++i)
#pragma unroll
      for (int j = 0; j < 4; ++j)
#pragma unroll
        for (int r = 0; r < 4; ++r) {
          int mm = m0 + wr + i * 16 + (lane >> 4) * 4 + r;
          int n = n0 + wc + j * 16 + lq;
          C[(size_t)mm * 2048 + n] = f2b(acc[i][j][r]);
        }
  } else {
    __shared__ unsigned short tile[64][65];
    int id2 = blockIdx.x - 512;
    int t0 = (id2 & 31) * 64;
    int c0 = ((id2 >> 5) & 15) * 64;
    int b = id2 >> 9;
    int tx = threadIdx.x & 63, ty = threadIdx.x >> 6;
#pragma unroll
    for (int r = 0; r < 16; ++r) {
      int tt = ty * 16 + r;
      tile[tt][tx] = vb[((size_t)b * 2048 + t0 + tt) * 1024 + c0 + tx];
    }
    __syncthreads();
#pragma unroll
    for (int r = 0; r < 16; ++r) {
      int cc = ty * 16 + r;
      Vt[((size_t)b * 1024 + c0 + cc) * 2048 + t0 + tx] = tile[tx][cc];
    }
  }
}

// ---------------- 3) causal flash attention with ALiBi ----------------------
// R22: R21's zero-barrier direct-L2 structure + the piece whose absence made
// R21 regress (72.5 us, VALUBusy 19% — exposed per-tile L2 latency):
// ONE-TILE REGISTER PREFETCH. At tile kt's top, issue the 8 direct loads for
// tile kt+1 into a named "next" operand set (kcB/vcB, statically indexed);
// consume "cur" (kcA/vcA); copy B->A at tile end. Compiler's auto-waitcnt
// lands at the copy — ~1000+ cyc after issue, fully covered by compute.
// Result: R19's latency hiding with NO barriers / LDS traffic / DMA / vmcnt
// in the loop. VGPR ~150 (two operand sets) -> __launch_bounds__(256,3),
// 3 blocks/CU. LDS = 18 KB reduction scratch, ONE __syncthreads total.
// Keeps: k-split waves, swapped QK^T + in-register cvt_pk/permlane
// P-transpose, XCD-group + balanced-qt decode, exp2-direct, hoisted ALiBi,
// T5 setprio. Fallback if >46 us: revert to R10/R19 staged-DMA flash.
__global__ __launch_bounds__(256, 3) void k_flash(const unsigned short* __restrict__ qkb, // [2][2048][2048]
                                                  const unsigned short* __restrict__ Vt,  // [2][1024][2048]
                                                  unsigned short* __restrict__ y) {       // [2][2048][1024]
  __shared__ float red[2][64 * 36];              // k-half reduction scratch (18 KB)
  int id = blockIdx.x;
  int xcd = id & 7, s = id >> 3;
  int grp = xcd + 8 * (s & 3);                   // 32 (hd,b) groups, 4 per XCD
  int v = s >> 2, m = v & 7, t = v >> 3;         // per-CU balanced permutation
  int qt = (t == 0) ? (31 - m) : (t == 1) ? (16 + m) : (t == 2) ? (15 - m) : m;
  int hd = grp & 15, b = grp >> 4;
  int tid = threadIdx.x;
  int w = tid >> 6, lane = tid & 63;
  int quad = lane >> 4, lq = lane & 15, lk8 = quad * 8;
  int qh = w >> 1, kh = w & 1;                   // q-half / k-half of this wave
  const size_t rowb = (size_t)b * 2048;

  // per-lane global fragment bases (chunk = quad*8)
  const unsigned short* kbase = qkb + ((rowb + kh * 32 + lq) << 11) + 1024 + hd * 64 + quad * 8;
  const unsigned short* vbase = Vt + ((size_t)b * 1024 + hd * 64 + lq) * 2048 + kh * 32 + quad * 8;

  float slope = exp2f(-0.5f * (float)(hd + 1));  // ALiBi, H=16 power-of-2
  const float c1 = 0.125f * LOG2E;               // 1/sqrt(64) * log2(e)
  const float c2 = slope * LOG2E;
  const float c16 = 16.0f * c2;
  const float SHIFT = 16.0f;                     // fixed softmax shift (log2)

  bf16x8 ones;
#pragma unroll
  for (int i = 0; i < 8; ++i) ones[i] = (__bf16)1.0f;

  int q0 = qt * 64;
  int qrow = q0 + qh * 32;                       // wave's q-base
  bf16x8 qf[2][2];                               // [q-subtile][d-half]
#pragma unroll
  for (int qs2 = 0; qs2 < 2; ++qs2) {
    int qg = qrow + qs2 * 16 + lq;
    qf[qs2][0] = *(const bf16x8*)(qkb + ((rowb + qg) << 11) + hd * 64 + lk8);
    qf[qs2][1] = *(const bf16x8*)(qkb + ((rowb + qg) << 11) + hd * 64 + 32 + lk8);
  }
  // ALiBi: arg = S*c1 + base0[r] + c2*k0 + c16*(ks2 - qs2)
  int kq0 = kh * 32 + quad * 4 - qrow - lq;      // per-lane k-q offset
  float base0[4];
#pragma unroll
  for (int r = 0; r < 4; ++r) base0[r] = c2 * (float)(kq0 + r) - SHIFT;

  f32x4 o[4][2];                                 // [d-subtile][q-subtile]
  f32x4 o4[2];
#pragma unroll
  for (int r = 0; r < 4; ++r) { o4[0][r] = 0.f; o4[1][r] = 0.f; }
#pragma unroll
  for (int jj = 0; jj < 4; ++jj)
#pragma unroll
    for (int qs2 = 0; qs2 < 2; ++qs2)
#pragma unroll
      for (int r = 0; r < 4; ++r) o[jj][qs2][r] = 0.f;

  // ---- prologue: load tile 0 operands into the "cur" set ----
  bf16x8 kcA[2][2], vcA[4];                      // current-tile K/V fragments
  bf16x8 kcB[2][2], vcB[4];                      // next-tile (prefetch) fragments
#pragma unroll
  for (int ks2 = 0; ks2 < 2; ++ks2) {
    size_t ko = ((size_t)(ks2 * 16) << 11);
    kcA[ks2][0] = *(const bf16x8*)(kbase + ko);
    kcA[ks2][1] = *(const bf16x8*)(kbase + ko + 32);
  }
#pragma unroll
  for (int jj = 0; jj < 4; ++jj)
    vcA[jj] = *(const bf16x8*)(vbase + (size_t)(jj * 16) * 2048);

#pragma unroll 1
  for (int kt = 0; kt <= qt; ++kt) {
    int k0 = kt * 64;
    // prefetch tile kt+1 into the "next" set (direct L2 loads, no LDS)
    if (kt < qt) {
      int k1 = k0 + 64;
#pragma unroll
      for (int ks2 = 0; ks2 < 2; ++ks2) {
        size_t ko = ((size_t)(k1 + ks2 * 16) << 11);
        kcB[ks2][0] = *(const bf16x8*)(kbase + ko);
        kcB[ks2][1] = *(const bf16x8*)(kbase + ko + 32);
      }
#pragma unroll
      for (int jj = 0; jj < 4; ++jj)
        vcB[jj] = *(const bf16x8*)(vbase + (size_t)(jj * 16) * 2048 + k1);
    }
    // swapped QK^T: S^T[k][q] per (ks2, qs2) from cur K regs
    __builtin_amdgcn_s_setprio(1);
    f32x4 S[2][2];
#pragma unroll
    for (int ks2 = 0; ks2 < 2; ++ks2)
#pragma unroll
      for (int qs2 = 0; qs2 < 2; ++qs2) {
        f32x4 a;
#pragma unroll
        for (int r = 0; r < 4; ++r) a[r] = 0.f;
        a = __builtin_amdgcn_mfma_f32_16x16x32_bf16(kcA[ks2][0], qf[qs2][0], a, 0, 0, 0);
        a = __builtin_amdgcn_mfma_f32_16x16x32_bf16(kcA[ks2][1], qf[qs2][1], a, 0, 0, 0);
        S[ks2][qs2] = a;
      }
    __builtin_amdgcn_s_setprio(0);
    // p = exp2(score - SHIFT); masked cols -> 0 on the diagonal tile
    float bk = c2 * (float)k0;
    unsigned pk[2][2][2];                        // [ks2][qs2][gr]
    if (kt == qt) {
#pragma unroll
      for (int ks2 = 0; ks2 < 2; ++ks2)
#pragma unroll
        for (int qs2 = 0; qs2 < 2; ++qs2) {
          float p[4];
#pragma unroll
          for (int r = 0; r < 4; ++r) {
            float vv = S[ks2][qs2][r] * c1 + (base0[r] + bk + c16 * (float)(ks2 - qs2));
            vv = (k0 + kq0 + (ks2 - qs2) * 16 + r <= 0) ? vv : -1e30f;
            p[r] = exp2_fast(vv);
          }
          pk[ks2][qs2][0] = cvt_pk(p[0], p[1]);
          pk[ks2][qs2][1] = cvt_pk(p[2], p[3]);
        }
    } else {
#pragma unroll
      for (int ks2 = 0; ks2 < 2; ++ks2)
#pragma unroll
        for (int qs2 = 0; qs2 < 2; ++qs2) {
          float p[4];
#pragma unroll
          for (int r = 0; r < 4; ++r) {
            float vv = S[ks2][qs2][r] * c1 + (base0[r] + bk + c16 * (float)(ks2 - qs2));
            p[r] = exp2_fast(vv);
          }
          pk[ks2][qs2][0] = cvt_pk(p[0], p[1]);
          pk[ks2][qs2][1] = cvt_pk(p[2], p[3]);
        }
    }
    // build PV B-frags in registers (cvt_pk + permlane swaps)
    bf16x8 pf[2];                                // [q-subtile], K=32 = wave's k-half
#pragma unroll
    for (int qs2 = 0; qs2 < 2; ++qs2) {
      unsigned a0 = pk[0][qs2][0], b0 = pk[1][qs2][0];
      swap32(a0, b0); swap16(a0, b0);
      unsigned a1 = pk[0][qs2][1], b1 = pk[1][qs2][1];
      swap32(a1, b1); swap16(a1, b1);
      u32x4 tt; tt[0] = a0; tt[1] = a1; tt[2] = b0; tt[3] = b1;
      pf[qs2] = __builtin_bit_cast(bf16x8, tt);
    }
    // l[q] partial + PV partial from cur V regs
    __builtin_amdgcn_s_setprio(1);
    o4[0] = __builtin_amdgcn_mfma_f32_16x16x32_bf16(ones, pf[0], o4[0], 0, 0, 0);
    o4[1] = __builtin_amdgcn_mfma_f32_16x16x32_bf16(ones, pf[1], o4[1], 0, 0, 0);
#pragma unroll
    for (int jj = 0; jj < 4; ++jj) {
      o[jj][0] = __builtin_amdgcn_mfma_f32_16x16x32_bf16(vcA[jj], pf[0], o[jj][0], 0, 0, 0);
      o[jj][1] = __builtin_amdgcn_mfma_f32_16x16x32_bf16(vcA[jj], pf[1], o[jj][1], 0, 0, 0);
    }
    __builtin_amdgcn_s_setprio(0);
    // rotate prefetched operands into "cur" (waitcnt lands here, fully covered)
    if (kt < qt) {
#pragma unroll
      for (int ks2 = 0; ks2 < 2; ++ks2) {
        kcA[ks2][0] = kcB[ks2][0];
        kcA[ks2][1] = kcB[ks2][1];
      }
#pragma unroll
      for (int jj = 0; jj < 4; ++jj) vcA[jj] = vcB[jj];
    }
  }

  // ---- cross-wave k-half reduction (the kernel's ONLY barrier) ----
  float* rp = &red[qh][lane * 36];
  if (kh == 1) {
#pragma unroll
    for (int jj = 0; jj < 4; ++jj)
#pragma unroll
      for (int qs2 = 0; qs2 < 2; ++qs2)
#pragma unroll
        for (int r = 0; r < 4; ++r) rp[(jj * 2 + qs2) * 4 + r] = o[jj][qs2][r];
    rp[32] = o4[0][0];
    rp[33] = o4[1][0];
  }
  __syncthreads();
  if (kh == 0) {
#pragma unroll
    for (int jj = 0; jj < 4; ++jj)
#pragma unroll
      for (int qs2 = 0; qs2 < 2; ++qs2)
#pragma unroll
        for (int r = 0; r < 4; ++r) o[jj][qs2][r] += rp[(jj * 2 + qs2) * 4 + r];
    float inv0 = 1.0f / (o4[0][0] + rp[32]);
    float inv1 = 1.0f / (o4[1][0] + rp[33]);
    // epilogue: lane holds q = qrow + qs2*16 + lq, d = jj*16 + quad*4 + r
#pragma unroll
    for (int qs2 = 0; qs2 < 2; ++qs2) {
      float inv = qs2 ? inv1 : inv0;
      size_t base = ((rowb + qrow + qs2 * 16 + lq) << 10) + hd * 64 + quad * 4;
#pragma unroll
      for (int jj = 0; jj < 4; ++jj) {
        ushort4 pk4;
        pk4.x = f2b(o[jj][qs2][0] * inv);
        pk4.y = f2b(o[jj][qs2][1] * inv);
        pk4.z = f2b(o[jj][qs2][2] * inv);
        pk4.w = f2b(o[jj][qs2][3] * inv);
        *(ushort4*)(y + base + jj * 16) = pk4;
      }
    }
  }
}

// --- 4) out[b,t,i*64+d] = sum_j y[b,t,j*64+d] * proj_tmp[i*16+j]  (FP32 out) ---
__global__ __launch_bounds__(256) void k_proj(const unsigned short* __restrict__ yb,
                                              const float* __restrict__ pt,
                                              float* __restrict__ out) {
  __shared__ float s_pt[256];
  s_pt[threadIdx.x] = pt[threadIdx.x];
  __syncthreads();
  int g = blockIdx.x * 256 + threadIdx.x;
  int bt = g >> 6, d = g & 63;
  float yj[16];
#pragma unroll
  for (int j = 0; j < 16; ++j) yj[j] = b2f(yb[(size_t)bt * 1024 + j * 64 + d]);
#pragma unroll
  for (int i = 0; i < 16; ++i) {
    float s = 0.f;
#pragma unroll
    for (int j = 0; j < 16; ++j) s += yj[j] * s_pt[i * 16 + j];
    out[(size_t)bt * 1024 + i * 64 + d] = s;
  }
}

extern "C" void kernel_launch(void* const* d_in, const int* in_sizes, int n_in,
                              void* d_out, int out_size, void* d_ws, size_t ws_size,
                              hipStream_t stream) {
  const float* x  = (const float*)d_in[0];   // [2][2048][1024] fp32
  const float* W  = (const float*)d_in[1];   // [1024][2048] fp32
  const float* vt = (const float*)d_in[2];   // [16][16] fp32
  const float* pt = (const float*)d_in[3];   // [16][16] fp32
  float* out = (float*)d_out;                // fp32 out

  char* ws = (char*)d_ws;
  unsigned short* xb  = (unsigned short*)(ws);                 //  8 MiB, reused as y
  unsigned short* Wt  = (unsigned short*)(ws + (8u  << 20));   //  4 MiB
  unsigned short* qkb = (unsigned short*)(ws + (12u << 20));   // 16 MiB
  unsigned short* vb  = (unsigned short*)(ws + (28u << 20));   //  8 MiB
  unsigned short* Vtr = (unsigned short*)(ws + (36u << 20));   //  8 MiB
  unsigned short* yb  = xb;  // xb dead after GEMM; flash writes y there

  k_pre  <<<1536, 256, 0, stream>>>(x, vt, W, xb, vb, Wt);
  k_mid  <<<1536, 256, 0, stream>>>(xb, Wt, qkb, vb, Vtr);
  k_flash<<<1024, 256, 0, stream>>>(qkb, Vtr, yb);
  k_proj <<<1024, 256, 0, stream>>>(yb, pt, out);
}

// Round 16
// 148.792 us; speedup vs baseline: 1.2791x; 1.2791x over previous
//
#include <hip/hip_runtime.h>

typedef __attribute__((ext_vector_type(8))) __bf16 bf16x8;
typedef __attribute__((ext_vector_type(8))) unsigned short u16x8;
typedef __attribute__((ext_vector_type(4))) float f32x4;
typedef __attribute__((ext_vector_type(4))) unsigned int u32x4;

#define LOG2E 1.4426950408889634f

// async global -> LDS, 16 bytes per lane (dest must be wave-uniform base + lane*16)
#define GLDS16(gp, lp)                                                \
  __builtin_amdgcn_global_load_lds(                                   \
      (const __attribute__((address_space(1))) void*)(gp),            \
      (__attribute__((address_space(3))) void*)(lp), 16, 0, 0)

__device__ __forceinline__ unsigned short f2b(float f) {
  return __builtin_bit_cast(unsigned short, (__bf16)f);
}
__device__ __forceinline__ float b2f(unsigned short h) {
  return __uint_as_float(((unsigned)h) << 16);
}
// v_cvt_pk_bf16_f32: lo16 = bf16(a), hi16 = bf16(b)   (no builtin on gfx950)
__device__ __forceinline__ unsigned cvt_pk(float a, float b) {
  unsigned r;
  asm("v_cvt_pk_bf16_f32 %0, %1, %2" : "=v"(r) : "v"(a), "v"(b));
  return r;
}
__device__ __forceinline__ void swap32(unsigned& a, unsigned& b) {
  asm("v_permlane32_swap_b32 %0, %1" : "+v"(a), "+v"(b));
}
__device__ __forceinline__ void swap16(unsigned& a, unsigned& b) {
  asm("v_permlane16_swap_b32 %0, %1" : "+v"(a), "+v"(b));
}
// raw v_exp_f32 (args bounded; -1e30 -> 0 is the exact HW behavior)
__device__ __forceinline__ float exp2_fast(float x) {
#if __has_builtin(__builtin_amdgcn_exp2f)
  return __builtin_amdgcn_exp2f(x);
#else
  float r; asm("v_exp_f32 %0, %1" : "=v"(r) : "v"(x)); return r;
#endif
}

// -- 1) merged launch: [0,1024) xv: xb=bf16(x), v=x@v_tmp; [1024,1536) W transpose
__global__ __launch_bounds__(256) void k_pre(const float* __restrict__ x,
                                             const float* __restrict__ vt,
                                             const float* __restrict__ W,
                                             unsigned short* __restrict__ xb,
                                             unsigned short* __restrict__ vb,
                                             unsigned short* __restrict__ Wt) {
  if (blockIdx.x < 1024) {
    __shared__ float s_vt[256];
    s_vt[threadIdx.x] = vt[threadIdx.x];
    __syncthreads();
    int g = blockIdx.x * 256 + threadIdx.x;
    int bt = g >> 6, d = g & 63;
    const float* xp = x + (size_t)bt * 1024 + d;
    float xi[16];
#pragma unroll
    for (int i = 0; i < 16; ++i) xi[i] = xp[i * 64];
#pragma unroll
    for (int i = 0; i < 16; ++i) xb[(size_t)bt * 1024 + i * 64 + d] = f2b(xi[i]);
#pragma unroll
    for (int j = 0; j < 16; ++j) {
      float s = 0.f;
#pragma unroll
      for (int i = 0; i < 16; ++i) s += xi[i] * s_vt[i * 16 + j];
      vb[(size_t)bt * 1024 + j * 64 + d] = f2b(s);
    }
  } else {
    __shared__ unsigned short tile[64][65];
    int id2 = blockIdx.x - 1024;
    int n0 = (id2 & 31) * 64;
    int k0 = (id2 >> 5) * 64;
    int tx = threadIdx.x & 63, ty = threadIdx.x >> 6;
#pragma unroll
    for (int r = 0; r < 16; ++r) {
      int kk = ty * 16 + r;
      tile[kk][tx] = f2b(W[(size_t)(k0 + kk) * 2048 + n0 + tx]);
    }
    __syncthreads();
#pragma unroll
    for (int r = 0; r < 16; ++r) {
      int nn = ty * 16 + r;
      Wt[(size_t)(n0 + nn) * 1024 + k0 + tx] = tile[tx][nn];
    }
  }
}

// -- 2) merged launch: [0,512) GEMM qk = xb @ Wt^T (m97 DMA pattern);
//      [512,1536) vb -> Vt transpose (t-major for PV)
__global__ __launch_bounds__(256) void k_mid(const unsigned short* __restrict__ A,
                                             const unsigned short* __restrict__ Bt,
                                             unsigned short* __restrict__ C,
                                             const unsigned short* __restrict__ vb,
                                             unsigned short* __restrict__ Vt) {
  if (blockIdx.x < 512) {
    __shared__ unsigned short As[128 * 32];
    __shared__ unsigned short Bs[128 * 32];
    const int K = 1024;
    int m0 = (blockIdx.x & 31) * 128;
    int n0 = (blockIdx.x >> 5) * 128;
    int tid = threadIdx.x;
    int w = tid >> 6, lane = tid & 63;
    int lq = lane & 15, lk8 = (lane >> 4) * 8;
    int wr = (w >> 1) * 64, wc = (w & 1) * 64;
    f32x4 acc[4][4];
#pragma unroll
    for (int i = 0; i < 4; ++i)
#pragma unroll
      for (int j = 0; j < 4; ++j)
#pragma unroll
        for (int r = 0; r < 4; ++r) acc[i][j][r] = 0.f;

    for (int kk = 0; kk < K; kk += 32) {
      __syncthreads();
#pragma unroll
      for (int i = 0; i < 2; ++i) {
        int c = tid + 256 * i;
        int row = c >> 2, col = (c & 3) * 8;
        GLDS16(A + (size_t)(m0 + row) * K + kk + col, As + c * 8);
        GLDS16(Bt + (size_t)(n0 + row) * K + kk + col, Bs + c * 8);
      }
      __syncthreads();
      bf16x8 af[4], bf[4];
#pragma unroll
      for (int i = 0; i < 4; ++i) af[i] = *(const bf16x8*)(As + (wr + i * 16 + lq) * 32 + lk8);
#pragma unroll
      for (int j = 0; j < 4; ++j) bf[j] = *(const bf16x8*)(Bs + (wc + j * 16 + lq) * 32 + lk8);
#pragma unroll
      for (int i = 0; i < 4; ++i)
#pragma unroll
        for (int j = 0; j < 4; ++j)
          acc[i][j] = __builtin_amdgcn_mfma_f32_16x16x32_bf16(af[i], bf[j], acc[i][j], 0, 0, 0);
    }
#pragma unroll
    for (int i = 0; i < 4; ++i)
#pragma unroll
      for (int j = 0; j < 4; ++j)
#pragma unroll
        for (int r = 0; r < 4; ++r) {
          int mm = m0 + wr + i * 16 + (lane >> 4) * 4 + r;
          int n = n0 + wc + j * 16 + lq;
          C[(size_t)mm * 2048 + n] = f2b(acc[i][j][r]);
        }
  } else {
    __shared__ unsigned short tile[64][65];
    int id2 = blockIdx.x - 512;
    int t0 = (id2 & 31) * 64;
    int c0 = ((id2 >> 5) & 15) * 64;
    int b = id2 >> 9;
    int tx = threadIdx.x & 63, ty = threadIdx.x >> 6;
#pragma unroll
    for (int r = 0; r < 16; ++r) {
      int tt = ty * 16 + r;
      tile[tt][tx] = vb[((size_t)b * 2048 + t0 + tt) * 1024 + c0 + tx];
    }
    __syncthreads();
#pragma unroll
    for (int r = 0; r < 16; ++r) {
      int cc = ty * 16 + r;
      Vt[((size_t)b * 1024 + c0 + cc) * 2048 + t0 + tx] = tile[tx][cc];
    }
  }
}

// ---------------- 3) causal flash attention with ALiBi ----------------------
// R23 = REVERT to R19 (session-best: flash 44.8 us, total 149.6 us at R10).
// R21 (no staging, direct L2) regressed to 72 us — exposed per-tile L2
// latency; R22 (register prefetch) regressed to 82 us — operand-set rotation
// spilled to scratch (WRITE_SIZE 2x). Conclusion: global_load_lds staging is
// the only latency-hiding mechanism that works at this occupancy — prefetch
// lives outside the VGPR budget. Structure: 4 LDS buffers, DMA lead 3,
// counted vmcnt(8/4/0) so tile kt+1 is resident at tile kt's start; QK^T of
// kt+1 overlaps softmax/PV of kt (MFMA pipe || VALU pipe). k-split waves,
// swapped QK^T + in-register cvt_pk/permlane P-transpose, XOR bank swizzle,
// XCD-group + balanced-qt decode, exp2-direct, T5 setprio.
__global__ __launch_bounds__(256, 4) void k_flash(const unsigned short* __restrict__ qkb, // [2][2048][2048]
                                                  const unsigned short* __restrict__ Vt,  // [2][1024][2048]
                                                  unsigned short* __restrict__ y) {       // [2][2048][1024]
  __shared__ unsigned short Ks[4][2][64 * 32];   // [buf][half][k][d32 swz]
  __shared__ unsigned short Vs[4][2][64 * 32];   // [buf][half][d][t32 swz]
  int id = blockIdx.x;
  int xcd = id & 7, s = id >> 3;
  int grp = xcd + 8 * (s & 3);                   // 32 (hd,b) groups, 4 per XCD
  int v = s >> 2, m = v & 7, t = v >> 3;         // per-CU balanced permutation
  int qt = (t == 0) ? (31 - m) : (t == 1) ? (16 + m) : (t == 2) ? (15 - m) : m;
  int hd = grp & 15, b = grp >> 4;
  int tid = threadIdx.x;
  int w = tid >> 6, lane = tid & 63;
  int quad = lane >> 4, lq = lane & 15, lk8 = quad * 8;
  int xk8 = (quad ^ ((lq >> 1) & 3)) * 8;        // swizzled frag-read chunk
  int qh = w >> 1, kh = w & 1;                   // q-half / k-half of this wave
  int rs = tid >> 2;
  int csw = ((tid & 3) ^ ((tid >> 3) & 3)) * 8;  // swizzled DMA source chunk
  int ld = rs * 32 + (tid & 3) * 8;              // linear LDS dest (tid*16 B)
  const size_t rowb = (size_t)b * 2048;
  const size_t vrow = ((size_t)b * 1024 + hd * 64 + rs) * 2048 + csw;
  const size_t krow = ((rowb + rs) << 11) + 1024 + hd * 64 + csw;

  float slope = exp2f(-0.5f * (float)(hd + 1));  // ALiBi, H=16 power-of-2
  const float c1 = 0.125f * LOG2E;               // 1/sqrt(64) * log2(e)
  const float c2 = slope * LOG2E;
  const float c16 = 16.0f * c2;
  const float SHIFT = 16.0f;                     // fixed softmax shift (log2)

  bf16x8 ones;
#pragma unroll
  for (int i = 0; i < 8; ++i) ones[i] = (__bf16)1.0f;

  int q0 = qt * 64;
  int qrow = q0 + qh * 32;                       // wave's q-base
  bf16x8 qf[2][2];                               // [q-subtile][d-half]
#pragma unroll
  for (int qs2 = 0; qs2 < 2; ++qs2) {
    int qg = qrow + qs2 * 16 + lq;
    qf[qs2][0] = *(const bf16x8*)(qkb + ((rowb + qg) << 11) + hd * 64 + lk8);
    qf[qs2][1] = *(const bf16x8*)(qkb + ((rowb + qg) << 11) + hd * 64 + 32 + lk8);
  }
  // ALiBi: arg = S*c1 + base0[r] + c2*k0 + c16*(ks2 - qs2)
  int kq0 = kh * 32 + quad * 4 - qrow - lq;      // per-lane k-q offset
  float base0[4];
#pragma unroll
  for (int r = 0; r < 4; ++r) base0[r] = c2 * (float)(kq0 + r) - SHIFT;

  f32x4 o[4][2];                                 // [d-subtile][q-subtile]
  f32x4 o4[2];
#pragma unroll
  for (int r = 0; r < 4; ++r) { o4[0][r] = 0.f; o4[1][r] = 0.f; }
#pragma unroll
  for (int jj = 0; jj < 4; ++jj)
#pragma unroll
    for (int qs2 = 0; qs2 < 2; ++qs2)
#pragma unroll
      for (int r = 0; r < 4; ++r) o[jj][qs2][r] = 0.f;

  // ---- prologue: DMA tiles 0..min(2,qt); need t0 AND t1 resident ----
  GLDS16(qkb + krow,      &Ks[0][0][ld]);
  GLDS16(qkb + krow + 32, &Ks[0][1][ld]);
  GLDS16(Vt + vrow,       &Vs[0][0][ld]);
  GLDS16(Vt + vrow + 32,  &Vs[0][1][ld]);
  if (qt >= 1) {
    GLDS16(qkb + krow + ((size_t)64 << 11),      &Ks[1][0][ld]);
    GLDS16(qkb + krow + ((size_t)64 << 11) + 32, &Ks[1][1][ld]);
    GLDS16(Vt + vrow + 64,                       &Vs[1][0][ld]);
    GLDS16(Vt + vrow + 64 + 32,                  &Vs[1][1][ld]);
  }
  if (qt >= 2) {
    GLDS16(qkb + krow + ((size_t)128 << 11),      &Ks[2][0][ld]);
    GLDS16(qkb + krow + ((size_t)128 << 11) + 32, &Ks[2][1][ld]);
    GLDS16(Vt + vrow + 128,                       &Vs[2][0][ld]);
    GLDS16(Vt + vrow + 128 + 32,                  &Vs[2][1][ld]);
    asm volatile("s_waitcnt vmcnt(4)" ::: "memory");   // t0,t1 done; t2 in flight
  } else {
    asm volatile("s_waitcnt vmcnt(0)" ::: "memory");
  }
  __builtin_amdgcn_s_barrier();
  __builtin_amdgcn_sched_barrier(0);

  // ---- pre-loop: K(0) frags + S_cur = QK(tile 0) ----
  f32x4 Sc[2][2];
  {
    bf16x8 kc[2][2];
#pragma unroll
    for (int ks2 = 0; ks2 < 2; ++ks2) {
      u16x8 t0 = *(const u16x8*)(&Ks[0][0][(kh * 32 + ks2 * 16 + lq) * 32 + xk8]);
      u16x8 t1 = *(const u16x8*)(&Ks[0][1][(kh * 32 + ks2 * 16 + lq) * 32 + xk8]);
      kc[ks2][0] = __builtin_bit_cast(bf16x8, t0);
      kc[ks2][1] = __builtin_bit_cast(bf16x8, t1);
    }
    __builtin_amdgcn_s_setprio(1);
#pragma unroll
    for (int ks2 = 0; ks2 < 2; ++ks2)
#pragma unroll
      for (int qs2 = 0; qs2 < 2; ++qs2) {
        f32x4 a;
#pragma unroll
        for (int r = 0; r < 4; ++r) a[r] = 0.f;
        a = __builtin_amdgcn_mfma_f32_16x16x32_bf16(kc[ks2][0], qf[qs2][0], a, 0, 0, 0);
        a = __builtin_amdgcn_mfma_f32_16x16x32_bf16(kc[ks2][1], qf[qs2][1], a, 0, 0, 0);
        Sc[ks2][qs2] = a;
      }
    __builtin_amdgcn_s_setprio(0);
  }

#pragma unroll 1
  for (int kt = 0; kt <= qt; ++kt) {
    int k0 = kt * 64;
    int cb = kt & 3;                             // V-read buffer (tile kt)
    // DMA tile kt+3 into buffer (kt+3)&3 (lead 3)
    if (kt + 3 <= qt) {
      size_t koff = (size_t)(k0 + 192);
      int db = (kt + 3) & 3;
      GLDS16(qkb + krow + (koff << 11),      &Ks[db][0][ld]);
      GLDS16(qkb + krow + (koff << 11) + 32, &Ks[db][1][ld]);
      GLDS16(Vt + vrow + koff,               &Vs[db][0][ld]);
      GLDS16(Vt + vrow + koff + 32,          &Vs[db][1][ld]);
    }
    // softmax(S_cur): p = exp2(score - SHIFT); masked cols -> 0 on diagonal
    float bk = c2 * (float)k0;
    unsigned pk[2][2][2];                        // [ks2][qs2][gr]
    if (kt == qt) {
#pragma unroll
      for (int ks2 = 0; ks2 < 2; ++ks2)
#pragma unroll
        for (int qs2 = 0; qs2 < 2; ++qs2) {
          float p[4];
#pragma unroll
          for (int r = 0; r < 4; ++r) {
            float vv = Sc[ks2][qs2][r] * c1 + (base0[r] + bk + c16 * (float)(ks2 - qs2));
            vv = (k0 + kq0 + (ks2 - qs2) * 16 + r <= 0) ? vv : -1e30f;
            p[r] = exp2_fast(vv);
          }
          pk[ks2][qs2][0] = cvt_pk(p[0], p[1]);
          pk[ks2][qs2][1] = cvt_pk(p[2], p[3]);
        }
    } else {
#pragma unroll
      for (int ks2 = 0; ks2 < 2; ++ks2)
#pragma unroll
        for (int qs2 = 0; qs2 < 2; ++qs2) {
          float p[4];
#pragma unroll
          for (int r = 0; r < 4; ++r) {
            float vv = Sc[ks2][qs2][r] * c1 + (base0[r] + bk + c16 * (float)(ks2 - qs2));
            p[r] = exp2_fast(vv);
          }
          pk[ks2][qs2][0] = cvt_pk(p[0], p[1]);
          pk[ks2][qs2][1] = cvt_pk(p[2], p[3]);
        }
    }
    // overlapped QK^T for tile kt+1 (buffer (kt+1)&3 is resident by counted wait)
    f32x4 Sn[2][2];
    if (kt < qt) {
      int nb = (kt + 1) & 3;
      bf16x8 kn[2][2];
#pragma unroll
      for (int ks2 = 0; ks2 < 2; ++ks2) {
        u16x8 t0 = *(const u16x8*)(&Ks[nb][0][(kh * 32 + ks2 * 16 + lq) * 32 + xk8]);
        u16x8 t1 = *(const u16x8*)(&Ks[nb][1][(kh * 32 + ks2 * 16 + lq) * 32 + xk8]);
        kn[ks2][0] = __builtin_bit_cast(bf16x8, t0);
        kn[ks2][1] = __builtin_bit_cast(bf16x8, t1);
      }
      __builtin_amdgcn_s_setprio(1);
#pragma unroll
      for (int ks2 = 0; ks2 < 2; ++ks2)
#pragma unroll
        for (int qs2 = 0; qs2 < 2; ++qs2) {
          f32x4 a;
#pragma unroll
          for (int r = 0; r < 4; ++r) a[r] = 0.f;
          a = __builtin_amdgcn_mfma_f32_16x16x32_bf16(kn[ks2][0], qf[qs2][0], a, 0, 0, 0);
          a = __builtin_amdgcn_mfma_f32_16x16x32_bf16(kn[ks2][1], qf[qs2][1], a, 0, 0, 0);
          Sn[ks2][qs2] = a;
        }
      __builtin_amdgcn_s_setprio(0);
    }
    // build PV B-frags in registers
    bf16x8 pf[2];                                // [q-subtile], K=32 = wave's k-half
#pragma unroll
    for (int qs2 = 0; qs2 < 2; ++qs2) {
      unsigned a0 = pk[0][qs2][0], b0 = pk[1][qs2][0];
      swap32(a0, b0); swap16(a0, b0);
      unsigned a1 = pk[0][qs2][1], b1 = pk[1][qs2][1];
      swap32(a1, b1); swap16(a1, b1);
      u32x4 tt; tt[0] = a0; tt[1] = a1; tt[2] = b0; tt[3] = b1;
      pf[qs2] = __builtin_bit_cast(bf16x8, tt);
    }
    // l[q] partial + PV partial (V frags from buffer kt&3, this wave's k-half)
    __builtin_amdgcn_s_setprio(1);
    o4[0] = __builtin_amdgcn_mfma_f32_16x16x32_bf16(ones, pf[0], o4[0], 0, 0, 0);
    o4[1] = __builtin_amdgcn_mfma_f32_16x16x32_bf16(ones, pf[1], o4[1], 0, 0, 0);
#pragma unroll
    for (int jj = 0; jj < 4; ++jj) {
      u16x8 v0 = *(const u16x8*)(&Vs[cb][kh][(jj * 16 + lq) * 32 + xk8]);
      bf16x8 vf = __builtin_bit_cast(bf16x8, v0);
      o[jj][0] = __builtin_amdgcn_mfma_f32_16x16x32_bf16(vf, pf[0], o[jj][0], 0, 0, 0);
      o[jj][1] = __builtin_amdgcn_mfma_f32_16x16x32_bf16(vf, pf[1], o[jj][1], 0, 0, 0);
    }
    __builtin_amdgcn_s_setprio(0);
    // counted-vmcnt barrier sized so tile kt+2 is resident entering tile kt+1
    if (kt < qt) {
      int nf = qt - kt - 1;                      // tiles allowed in flight
      if (nf >= 2)      asm volatile("s_waitcnt vmcnt(8)" ::: "memory");
      else if (nf == 1) asm volatile("s_waitcnt vmcnt(4)" ::: "memory");
      else              asm volatile("s_waitcnt vmcnt(0)" ::: "memory");
      __builtin_amdgcn_s_barrier();
      __builtin_amdgcn_sched_barrier(0);
#pragma unroll
      for (int ks2 = 0; ks2 < 2; ++ks2)
#pragma unroll
        for (int qs2 = 0; qs2 < 2; ++qs2) Sc[ks2][qs2] = Sn[ks2][qs2];
    }
  }

  // ---- cross-wave k-half reduction through LDS (Ks/Vs are dead) ----
  __syncthreads();                               // all tile reads done
  float* red0 = (float*)&Ks[0][0][0];            // qh=0
  float* red1 = (float*)&Vs[0][0][0];            // qh=1
  float* red = (qh ? red1 : red0) + lane * 36;
  if (kh == 1) {
#pragma unroll
    for (int jj = 0; jj < 4; ++jj)
#pragma unroll
      for (int qs2 = 0; qs2 < 2; ++qs2)
#pragma unroll
        for (int r = 0; r < 4; ++r) red[(jj * 2 + qs2) * 4 + r] = o[jj][qs2][r];
    red[32] = o4[0][0];
    red[33] = o4[1][0];
  }
  __syncthreads();
  if (kh == 0) {
#pragma unroll
    for (int jj = 0; jj < 4; ++jj)
#pragma unroll
      for (int qs2 = 0; qs2 < 2; ++qs2)
#pragma unroll
        for (int r = 0; r < 4; ++r) o[jj][qs2][r] += red[(jj * 2 + qs2) * 4 + r];
    float inv0 = 1.0f / (o4[0][0] + red[32]);
    float inv1 = 1.0f / (o4[1][0] + red[33]);
    // epilogue: lane holds q = qrow + qs2*16 + lq, d = jj*16 + quad*4 + r
#pragma unroll
    for (int qs2 = 0; qs2 < 2; ++qs2) {
      float inv = qs2 ? inv1 : inv0;
      size_t base = ((rowb + qrow + qs2 * 16 + lq) << 10) + hd * 64 + quad * 4;
#pragma unroll
      for (int jj = 0; jj < 4; ++jj) {
        ushort4 pk4;
        pk4.x = f2b(o[jj][qs2][0] * inv);
        pk4.y = f2b(o[jj][qs2][1] * inv);
        pk4.z = f2b(o[jj][qs2][2] * inv);
        pk4.w = f2b(o[jj][qs2][3] * inv);
        *(ushort4*)(y + base + jj * 16) = pk4;
      }
    }
  }
}

// --- 4) out[b,t,i*64+d] = sum_j y[b,t,j*64+d] * proj_tmp[i*16+j]  (FP32 out) ---
__global__ __launch_bounds__(256) void k_proj(const unsigned short* __restrict__ yb,
                                              const float* __restrict__ pt,
                                              float* __restrict__ out) {
  __shared__ float s_pt[256];
  s_pt[threadIdx.x] = pt[threadIdx.x];
  __syncthreads();
  int g = blockIdx.x * 256 + threadIdx.x;
  int bt = g >> 6, d = g & 63;
  float yj[16];
#pragma unroll
  for (int j = 0; j < 16; ++j) yj[j] = b2f(yb[(size_t)bt * 1024 + j * 64 + d]);
#pragma unroll
  for (int i = 0; i < 16; ++i) {
    float s = 0.f;
#pragma unroll
    for (int j = 0; j < 16; ++j) s += yj[j] * s_pt[i * 16 + j];
    out[(size_t)bt * 1024 + i * 64 + d] = s;
  }
}

extern "C" void kernel_launch(void* const* d_in, const int* in_sizes, int n_in,
                              void* d_out, int out_size, void* d_ws, size_t ws_size,
                              hipStream_t stream) {
  const float* x  = (const float*)d_in[0];   // [2][2048][1024] fp32
  const float* W  = (const float*)d_in[1];   // [1024][2048] fp32
  const float* vt = (const float*)d_in[2];   // [16][16] fp32
  const float* pt = (const float*)d_in[3];   // [16][16] fp32
  float* out = (float*)d_out;                // fp32 out

  char* ws = (char*)d_ws;
  unsigned short* xb  = (unsigned short*)(ws);                 //  8 MiB, reused as y
  unsigned short* Wt  = (unsigned short*)(ws + (8u  << 20));   //  4 MiB
  unsigned short* qkb = (unsigned short*)(ws + (12u << 20));   // 16 MiB
  unsigned short* vb  = (unsigned short*)(ws + (28u << 20));   //  8 MiB
  unsigned short* Vtr = (unsigned short*)(ws + (36u << 20));   //  8 MiB
  unsigned short* yb  = xb;  // xb dead after GEMM; flash writes y there

  k_pre  <<<1536, 256, 0, stream>>>(x, vt, W, xb, vb, Wt);
  k_mid  <<<1536, 256, 0, stream>>>(xb, Wt, qkb, vb, Vtr);
  k_flash<<<1024, 256, 0, stream>>>(qkb, Vtr, yb);
  k_proj <<<1024, 256, 0, stream>>>(yb, pt, out);
}